// Round 4
// baseline (281.845 us; speedup 1.0000x reference)
//
#include <hip/hip_runtime.h>
#include <math.h>

#define N_NODES 10000
#define N_EDGES 160000
#define F 128
#define F4 512

static constexpr float TWO_PI_OVER_L = 6.283185307179586f / 10.0f;

typedef __attribute__((ext_vector_type(8))) short bf16x8;
typedef __attribute__((ext_vector_type(4))) float f32x4;

__device__ __forceinline__ float silu_f(float x) { return x / (1.0f + __expf(-x)); }

__device__ __forceinline__ float bf2f(unsigned int u) {
    union { unsigned int i; float f; } x; x.i = u << 16; return x.f;
}
__device__ __forceinline__ unsigned short f2bf(float v) {
    unsigned int u = __float_as_uint(v);
    u += 0x7fff + ((u >> 16) & 1);           // round-to-nearest-even
    return (unsigned short)(u >> 16);
}

__device__ __forceinline__ void ld8bf(const unsigned short* p, float* o) {
    const uint4 u = *(const uint4*)p;
    o[0] = bf2f(u.x & 0xffff); o[1] = bf2f(u.x >> 16);
    o[2] = bf2f(u.y & 0xffff); o[3] = bf2f(u.y >> 16);
    o[4] = bf2f(u.z & 0xffff); o[5] = bf2f(u.z >> 16);
    o[6] = bf2f(u.w & 0xffff); o[7] = bf2f(u.w >> 16);
}

// ---------------- weight packing: W[K x N] f32 -> fragment-major bf16 ----------------
// packed[(nt*4+kk)*64 + lane][j] = W[kk*32 + (lane>>4)*8 + j][nt*16 + (lane&15)]
__global__ void pack_kernel(const float* __restrict__ W, int N,
                            unsigned short* __restrict__ out)
{
    const int idx = blockIdx.x * 256 + threadIdx.x;
    const int total = (N >> 4) * 4 * 64;
    if (idx >= total) return;
    const int lane = idx & 63;
    const int frag = idx >> 6;
    const int kk = frag & 3, nt = frag >> 2;
    const int k0 = kk * 32 + ((lane >> 4) << 3);
    const int n  = (nt << 4) + (lane & 15);
    unsigned short tmp[8];
#pragma unroll
    for (int j = 0; j < 8; ++j) tmp[j] = f2bf(W[(size_t)(k0 + j) * N + n]);
    uint4* o = (uint4*)(out + (size_t)idx * 8);
    *o = *(const uint4*)tmp;
}

// ---------------- CSR build ----------------
__global__ void hist_kernel(const int* __restrict__ ei, int* __restrict__ counts) {
    const int e = blockIdx.x * 256 + threadIdx.x;
    atomicAdd(&counts[ei[N_EDGES + e]], 1);
}

#define SCAN_CHUNK 40
__global__ __launch_bounds__(256) void scan_kernel(const int* __restrict__ counts,
                                                   int* __restrict__ offsets,
                                                   int* __restrict__ cursor)
{
    __shared__ int part[256];
    const int t = threadIdx.x;
    const int base = t * SCAN_CHUNK;
    int s = 0;
    for (int i = 0; i < SCAN_CHUNK; ++i) {
        const int idx = base + i;
        if (idx < N_NODES) s += counts[idx];
    }
    part[t] = s;
    __syncthreads();
    for (int d = 1; d < 256; d <<= 1) {
        int v = 0;
        if (t >= d) v = part[t - d];
        __syncthreads();
        part[t] += v;
        __syncthreads();
    }
    int run = (t == 0) ? 0 : part[t - 1];
    for (int i = 0; i < SCAN_CHUNK; ++i) {
        const int idx = base + i;
        if (idx < N_NODES) {
            offsets[idx] = run;
            cursor[idx] = run;
            run += counts[idx];
        }
    }
    if (t == 255) offsets[N_NODES] = part[255];
}

__global__ void slot_kernel(const int* __restrict__ ei, int* __restrict__ cursor,
                            int* __restrict__ csr) {
    const int e = blockIdx.x * 256 + threadIdx.x;
    const int dst = ei[N_EDGES + e];
    const int s = atomicAdd(&cursor[dst], 1);
    csr[s] = e;
}

// ---------------- fused 2-layer MLP via MFMA (32 rows/wave) ----------------
// MODE 0: node path. A = inv (f32 rows), out = phi = (silu(inv@pw1+b1))@pw2+b2
// MODE 1: edge path. A = PE(dist) in-register, out = mraw = silu(PE@ww1+b1)@ww2+b2
template <int MODE>
__global__ __launch_bounds__(256) void mlp_gemm_kernel(
    const float* __restrict__ xin,            // MODE0: inv[N,F]; MODE1: dist[E]
    const unsigned short* __restrict__ w1p, const float* __restrict__ b1,
    const unsigned short* __restrict__ w2p, const float* __restrict__ b2,
    unsigned short* __restrict__ out, const int nrows)
{
    __shared__ char s_h[4][8192];             // per-wave 32x128 bf16, XOR-swizzled
    const int t = threadIdx.x;
    const int w = t >> 6, l = t & 63;
    const int rb = blockIdx.x * 128 + w * 32; // wave's base row (2 tiles of 16)
    const int lr = l & 15;
    const int hi = l >> 4;                    // 0..3
    const int kb = hi << 3;                   // 0,8,16,24
    char* sh = s_h[w];

    // ---- A fragments: a[tile][kk] ----
    bf16x8 a[2][4];
    if (MODE == 0) {
#pragma unroll
        for (int T = 0; T < 2; ++T) {
            int row = rb + T * 16 + lr;
            if (row > nrows - 1) row = nrows - 1;
            const float* xr = xin + (size_t)row * F;
#pragma unroll
            for (int kk = 0; kk < 4; ++kk) {
                const float4 v0 = *(const float4*)(xr + kk * 32 + kb);
                const float4 v1 = *(const float4*)(xr + kk * 32 + kb + 4);
                bf16x8 av;
                av[0] = (short)f2bf(v0.x); av[1] = (short)f2bf(v0.y);
                av[2] = (short)f2bf(v0.z); av[3] = (short)f2bf(v0.w);
                av[4] = (short)f2bf(v1.x); av[5] = (short)f2bf(v1.y);
                av[6] = (short)f2bf(v1.z); av[7] = (short)f2bf(v1.w);
                a[T][kk] = av;
            }
        }
    } else {
#pragma unroll
        for (int T = 0; T < 2; ++T) {
            const int row = rb + T * 16 + lr;
            const float th = xin[row] * TWO_PI_OVER_L;
            // base ranks: hi*4 + 1 + i (i=0..3); kk adds 16 -> rotate by 16*th
            float sv[4], cv[4];
            const float c0 = (float)(hi * 4 + 1);
#pragma unroll
            for (int i = 0; i < 4; ++i)
                sincosf(th * (c0 + (float)i), &sv[i], &cv[i]);
            float s16, c16;
            sincosf(th * 16.0f, &s16, &c16);
#pragma unroll
            for (int kk = 0; kk < 4; ++kk) {
                bf16x8 av;
#pragma unroll
                for (int i = 0; i < 4; ++i) {
                    av[2 * i]     = (short)f2bf(sv[i]);
                    av[2 * i + 1] = (short)f2bf(cv[i]);
                }
                a[T][kk] = av;
                if (kk < 3) {
#pragma unroll
                    for (int i = 0; i < 4; ++i) {
                        const float ns = sv[i] * c16 + cv[i] * s16;
                        cv[i] = cv[i] * c16 - sv[i] * s16;
                        sv[i] = ns;
                    }
                }
            }
        }
    }

    const bf16x8* B1 = (const bf16x8*)w1p;
    const bf16x8* B2 = (const bf16x8*)w2p;

    // ---- GEMM1: H(32x128) = silu(A @ W1 + b1) -> swizzled LDS ----
#pragma unroll
    for (int nt = 0; nt < 8; ++nt) {
        const int n = nt * 16 + lr;
        const float bias = b1[n];
        bf16x8 bfr[4];
#pragma unroll
        for (int kk = 0; kk < 4; ++kk) bfr[kk] = B1[(nt * 4 + kk) * 64 + l];
        f32x4 acc[2];
        acc[0] = f32x4{ bias, bias, bias, bias };
        acc[1] = acc[0];
#pragma unroll
        for (int kk = 0; kk < 4; ++kk) {
            acc[0] = __builtin_amdgcn_mfma_f32_16x16x32_bf16(a[0][kk], bfr[kk], acc[0], 0, 0, 0);
            acc[1] = __builtin_amdgcn_mfma_f32_16x16x32_bf16(a[1][kk], bfr[kk], acc[1], 0, 0, 0);
        }
#pragma unroll
        for (int T = 0; T < 2; ++T)
#pragma unroll
            for (int r = 0; r < 4; ++r) {
                const int row = T * 16 + hi * 4 + r;
                const int byte = (row * 256 + n * 2) ^ ((row & 7) << 4);
                *(unsigned short*)(sh + byte) = f2bf(silu_f(acc[T][r]));
            }
    }

    // ---- A2 fragments from LDS (swizzled ds_read_b128) ----
    bf16x8 a2[2][4];
#pragma unroll
    for (int T = 0; T < 2; ++T)
#pragma unroll
        for (int kk = 0; kk < 4; ++kk) {
            const int row = T * 16 + lr;
            const int byte = (row * 256 + (kk * 32 + kb) * 2) ^ ((row & 7) << 4);
            a2[T][kk] = *(const bf16x8*)(sh + byte);
        }

    // ---- GEMM2: M(32x512) = H @ W2 + b2 ----
#pragma unroll 4
    for (int nt = 0; nt < 32; ++nt) {
        const int n = nt * 16 + lr;
        const float bias = b2[n];
        bf16x8 bfr[4];
#pragma unroll
        for (int kk = 0; kk < 4; ++kk) bfr[kk] = B2[(nt * 4 + kk) * 64 + l];
        f32x4 acc[2];
        acc[0] = f32x4{ bias, bias, bias, bias };
        acc[1] = acc[0];
#pragma unroll
        for (int kk = 0; kk < 4; ++kk) {
            acc[0] = __builtin_amdgcn_mfma_f32_16x16x32_bf16(a2[0][kk], bfr[kk], acc[0], 0, 0, 0);
            acc[1] = __builtin_amdgcn_mfma_f32_16x16x32_bf16(a2[1][kk], bfr[kk], acc[1], 0, 0, 0);
        }
#pragma unroll
        for (int T = 0; T < 2; ++T)
#pragma unroll
            for (int r = 0; r < 4; ++r) {
                const int grow = rb + T * 16 + hi * 4 + r;
                if (MODE == 0 && grow >= nrows) continue;
                out[(size_t)grow * F4 + n] = f2bf(acc[T][r]);
            }
    }
}

// ---------------- per-node gather: 8 features/thread, phi multiply fused ----------------
__global__ __launch_bounds__(256) void gather_kernel(
    const int* __restrict__ ei, const float* __restrict__ dirv,
    const int* __restrict__ offsets, const int* __restrict__ csr,
    const unsigned short* __restrict__ m, const unsigned short* __restrict__ phi,
    const float* __restrict__ inv, const float* __restrict__ equiv,
    float* __restrict__ out_v, float* __restrict__ out_s)
{
    const int t = threadIdx.x;
    const int n = blockIdx.x * 16 + (t >> 4);
    const int f0 = (t & 15) * 8;
    const int beg = offsets[n], end = offsets[n + 1];

    float A0[8], A1[8], A2[8], W0[8], W1[8], W2[8], SS[8];
#pragma unroll
    for (int j = 0; j < 8; ++j) {
        A0[j] = A1[j] = A2[j] = W0[j] = W1[j] = W2[j] = SS[j] = 0.f;
    }

    for (int si = beg; si < end; ++si) {
        const int e = csr[si];
        const int src = ei[e];
        const float d0 = dirv[e * 3 + 0];
        const float d1 = dirv[e * 3 + 1];
        const float d2 = dirv[e * 3 + 2];

        const unsigned short* mr = m + (size_t)e * F4 + f0;
        const unsigned short* pr = phi + (size_t)src * F4 + f0;
        float g[8], cg[8], sed[8], sf[8], pg[8], pcg[8], psed[8], psf[8];
        ld8bf(mr, g);  ld8bf(mr + 128, cg);  ld8bf(mr + 256, sed);  ld8bf(mr + 384, sf);
        ld8bf(pr, pg); ld8bf(pr + 128, pcg); ld8bf(pr + 256, psed); ld8bf(pr + 384, psf);

        float ev[24];
        const float* es = equiv + ((size_t)src * F + f0) * 3;
#pragma unroll
        for (int q = 0; q < 6; ++q) *(float4*)&ev[q * 4] = *(const float4*)(es + q * 4);
        float iv[8];
        const float* ip = inv + (size_t)src * F + f0;
        *(float4*)&iv[0] = *(const float4*)(ip);
        *(float4*)&iv[4] = *(const float4*)(ip + 4);

#pragma unroll
        for (int j = 0; j < 8; ++j) {
            const float gg   = g[j] * pg[j];
            const float cgg  = cg[j] * pcg[j];
            const float sedv = sed[j] * psed[j];
            const float sfv  = sf[j] * psf[j];
            A0[j] = fmaf(gg, ev[j * 3 + 0], fmaf(sedv, d0, A0[j]));
            A1[j] = fmaf(gg, ev[j * 3 + 1], fmaf(sedv, d1, A1[j]));
            A2[j] = fmaf(gg, ev[j * 3 + 2], fmaf(sedv, d2, A2[j]));
            W0[j] = fmaf(cgg, d0, W0[j]);
            W1[j] = fmaf(cgg, d1, W1[j]);
            W2[j] = fmaf(cgg, d2, W2[j]);
            SS[j] = fmaf(sfv, iv[j], SS[j]);
        }
    }

    // epilogue: residual base + cross(w, equiv[n])
    float bv[24];
    const float* eb = equiv + ((size_t)n * F + f0) * 3;
#pragma unroll
    for (int q = 0; q < 6; ++q) *(float4*)&bv[q * 4] = *(const float4*)(eb + q * 4);
    float ov[24];
#pragma unroll
    for (int j = 0; j < 8; ++j) {
        const float bx = bv[j * 3 + 0], by = bv[j * 3 + 1], bz = bv[j * 3 + 2];
        ov[j * 3 + 0] = bx + A0[j] + (W1[j] * bz - W2[j] * by);
        ov[j * 3 + 1] = by + A1[j] + (W2[j] * bx - W0[j] * bz);
        ov[j * 3 + 2] = bz + A2[j] + (W0[j] * by - W1[j] * bx);
    }
    float* op = out_v + ((size_t)n * F + f0) * 3;
#pragma unroll
    for (int q = 0; q < 6; ++q) *(float4*)(op + q * 4) = *(const float4*)&ov[q * 4];

    float ivb[8];
    const float* ib = inv + (size_t)n * F + f0;
    *(float4*)&ivb[0] = *(const float4*)(ib);
    *(float4*)&ivb[4] = *(const float4*)(ib + 4);
    float os[8];
#pragma unroll
    for (int j = 0; j < 8; ++j) os[j] = ivb[j] + SS[j];
    float* sp = out_s + (size_t)n * F + f0;
    *(float4*)(sp)     = *(const float4*)&os[0];
    *(float4*)(sp + 4) = *(const float4*)&os[4];
}

extern "C" void kernel_launch(void* const* d_in, const int* in_sizes, int n_in,
                              void* d_out, int out_size, void* d_ws, size_t ws_size,
                              hipStream_t stream)
{
    const int*   ei    = (const int*)d_in[0];
    const float* dist  = (const float*)d_in[1];
    const float* dirv  = (const float*)d_in[2];
    const float* inv   = (const float*)d_in[3];
    const float* equiv = (const float*)d_in[4];
    const float* pw1   = (const float*)d_in[5];
    const float* pb1   = (const float*)d_in[6];
    const float* pw2   = (const float*)d_in[7];
    const float* pb2   = (const float*)d_in[8];
    const float* ww1   = (const float*)d_in[9];
    const float* wb1   = (const float*)d_in[10];
    const float* ww2   = (const float*)d_in[11];
    const float* wb2   = (const float*)d_in[12];

    float* out_v = (float*)d_out;
    float* out_s = out_v + (size_t)N_NODES * F * 3;

    char* base = (char*)d_ws;
    size_t off = 0;
    auto take = [&](size_t bytes) -> void* {
        void* p = base + off;
        off = (off + bytes + 255) & ~(size_t)255;
        return p;
    };
    int* counts  = (int*)take((size_t)N_NODES * 4);
    int* offsets = (int*)take((size_t)(N_NODES + 1) * 4);
    int* cursor  = (int*)take((size_t)N_NODES * 4);
    int* csr     = (int*)take((size_t)N_EDGES * 4);
    unsigned short* phi  = (unsigned short*)take((size_t)N_NODES * F4 * 2);
    unsigned short* ww1p = (unsigned short*)take((size_t)F * F * 2);
    unsigned short* ww2p = (unsigned short*)take((size_t)F * F4 * 2);
    unsigned short* pw1p = (unsigned short*)take((size_t)F * F * 2);
    unsigned short* pw2p = (unsigned short*)take((size_t)F * F4 * 2);
    unsigned short* m    = (unsigned short*)take((size_t)N_EDGES * F4 * 2);
    (void)ws_size;

    hipMemsetAsync(counts, 0, (size_t)N_NODES * 4, stream);
    hist_kernel<<<N_EDGES / 256, 256, 0, stream>>>(ei, counts);
    scan_kernel<<<1, 256, 0, stream>>>(counts, offsets, cursor);
    slot_kernel<<<N_EDGES / 256, 256, 0, stream>>>(ei, cursor, csr);

    pack_kernel<<<8, 256, 0, stream>>>(ww1, F, ww1p);
    pack_kernel<<<32, 256, 0, stream>>>(ww2, F4, ww2p);
    pack_kernel<<<8, 256, 0, stream>>>(pw1, F, pw1p);
    pack_kernel<<<32, 256, 0, stream>>>(pw2, F4, pw2p);

    mlp_gemm_kernel<0><<<(N_NODES + 127) / 128, 256, 0, stream>>>(
        inv, pw1p, pb1, pw2p, pb2, phi, N_NODES);
    mlp_gemm_kernel<1><<<N_EDGES / 128, 256, 0, stream>>>(
        dist, ww1p, wb1, ww2p, wb2, m, N_EDGES);

    gather_kernel<<<N_NODES / 16, 256, 0, stream>>>(
        ei, dirv, offsets, csr, m, phi, inv, equiv, out_v, out_s);
}

// Round 5
// 260.602 us; speedup vs baseline: 1.0815x; 1.0815x over previous
//
#include <hip/hip_runtime.h>
#include <math.h>

#define N_NODES 10000
#define N_EDGES 160000
#define F 128
#define F4 512

static constexpr float TWO_PI_OVER_L = 6.283185307179586f / 10.0f;

typedef __attribute__((ext_vector_type(8))) short bf16x8;
typedef __attribute__((ext_vector_type(4))) float f32x4;

__device__ __forceinline__ float silu_f(float x) { return x / (1.0f + __expf(-x)); }

__device__ __forceinline__ float bf2f(unsigned int u) {
    union { unsigned int i; float f; } x; x.i = u << 16; return x.f;
}
__device__ __forceinline__ unsigned short f2bf(float v) {
    unsigned int u = __float_as_uint(v);
    u += 0x7fff + ((u >> 16) & 1);           // round-to-nearest-even
    return (unsigned short)(u >> 16);
}

__device__ __forceinline__ void ld4bf(const unsigned short* p, float* o) {
    const uint2 u = *(const uint2*)p;
    o[0] = bf2f(u.x & 0xffff); o[1] = bf2f(u.x >> 16);
    o[2] = bf2f(u.y & 0xffff); o[3] = bf2f(u.y >> 16);
}

// ---------------- weight packing: W[K x N] f32 -> fragment-major bf16 ----------------
// packed[(nt*4+kk)*64 + lane][j] = W[kk*32 + (lane>>4)*8 + j][nt*16 + (lane&15)]
__device__ __forceinline__ void pack_one(const float* __restrict__ W, int N,
                                         unsigned short* __restrict__ out, int idx)
{
    const int lane = idx & 63;
    const int frag = idx >> 6;
    const int kk = frag & 3, nt = frag >> 2;
    const int k0 = kk * 32 + ((lane >> 4) << 3);
    const int n  = (nt << 4) + (lane & 15);
    unsigned short tmp[8];
#pragma unroll
    for (int j = 0; j < 8; ++j) tmp[j] = f2bf(W[(size_t)(k0 + j) * N + n]);
    uint4* o = (uint4*)(out + (size_t)idx * 8);
    *o = *(const uint4*)tmp;
}

// sections: blocks [0,8) ww1, [8,40) ww2, [40,48) pw1, [48,80) pw2
__global__ void pack_all_kernel(
    const float* __restrict__ ww1, unsigned short* __restrict__ ww1p,
    const float* __restrict__ ww2, unsigned short* __restrict__ ww2p,
    const float* __restrict__ pw1, unsigned short* __restrict__ pw1p,
    const float* __restrict__ pw2, unsigned short* __restrict__ pw2p)
{
    const int b = blockIdx.x, t = threadIdx.x;
    if (b < 8)       pack_one(ww1, F,  ww1p, b * 256 + t);
    else if (b < 40) pack_one(ww2, F4, ww2p, (b - 8) * 256 + t);
    else if (b < 48) pack_one(pw1, F,  pw1p, (b - 40) * 256 + t);
    else             pack_one(pw2, F4, pw2p, (b - 48) * 256 + t);
}

// ---------------- CSR build ----------------
__global__ void hist_kernel(const int* __restrict__ ei, int* __restrict__ counts) {
    const int e = blockIdx.x * 256 + threadIdx.x;
    atomicAdd(&counts[ei[N_EDGES + e]], 1);
}

#define SCAN_CHUNK 40
__global__ __launch_bounds__(256) void scan_kernel(const int* __restrict__ counts,
                                                   int* __restrict__ offsets,
                                                   int* __restrict__ cursor)
{
    __shared__ int part[256];
    const int t = threadIdx.x;
    const int base = t * SCAN_CHUNK;
    int s = 0;
    for (int i = 0; i < SCAN_CHUNK; ++i) {
        const int idx = base + i;
        if (idx < N_NODES) s += counts[idx];
    }
    part[t] = s;
    __syncthreads();
    for (int d = 1; d < 256; d <<= 1) {
        int v = 0;
        if (t >= d) v = part[t - d];
        __syncthreads();
        part[t] += v;
        __syncthreads();
    }
    int run = (t == 0) ? 0 : part[t - 1];
    for (int i = 0; i < SCAN_CHUNK; ++i) {
        const int idx = base + i;
        if (idx < N_NODES) {
            offsets[idx] = run;
            cursor[idx] = run;
            run += counts[idx];
        }
    }
    if (t == 255) offsets[N_NODES] = part[255];
}

// scatter edges into CSR slots; emit CSR-ordered dist and per-edge header
__global__ void slot_kernel(const int* __restrict__ ei, const float* __restrict__ dist,
                            const float* __restrict__ dirv, int* __restrict__ cursor,
                            float* __restrict__ dist_csr, float4* __restrict__ hdr)
{
    const int e = blockIdx.x * 256 + threadIdx.x;
    const int src = ei[e];
    const int dst = ei[N_EDGES + e];
    const int s = atomicAdd(&cursor[dst], 1);
    dist_csr[s] = dist[e];
    hdr[s] = make_float4(__int_as_float(src),
                         dirv[e * 3 + 0], dirv[e * 3 + 1], dirv[e * 3 + 2]);
}

// ---------------- fused 2-layer MLP via MFMA (32 rows/wave) ----------------
// MODE 0: node path. A = inv (f32 rows), out = phi = (silu(inv@pw1+b1))@pw2+b2
// MODE 1: edge path. A = PE(dist_csr) in-register, out = m = silu(PE@ww1+b1)@ww2+b2
template <int MODE>
__global__ __launch_bounds__(256) void mlp_gemm_kernel(
    const float* __restrict__ xin,            // MODE0: inv[N,F]; MODE1: dist_csr[E]
    const unsigned short* __restrict__ w1p, const float* __restrict__ b1,
    const unsigned short* __restrict__ w2p, const float* __restrict__ b2,
    unsigned short* __restrict__ out, const int nrows)
{
    __shared__ char s_h[4][8192];             // per-wave 32x128 bf16, XOR-swizzled
    const int t = threadIdx.x;
    const int w = t >> 6, l = t & 63;
    const int rb = blockIdx.x * 128 + w * 32; // wave's base row (2 tiles of 16)
    const int lr = l & 15;
    const int hi = l >> 4;                    // 0..3
    const int kb = hi << 3;                   // 0,8,16,24
    char* sh = s_h[w];

    // ---- A fragments: a[tile][kk] ----
    bf16x8 a[2][4];
    if (MODE == 0) {
#pragma unroll
        for (int T = 0; T < 2; ++T) {
            int row = rb + T * 16 + lr;
            if (row > nrows - 1) row = nrows - 1;
            const float* xr = xin + (size_t)row * F;
#pragma unroll
            for (int kk = 0; kk < 4; ++kk) {
                const float4 v0 = *(const float4*)(xr + kk * 32 + kb);
                const float4 v1 = *(const float4*)(xr + kk * 32 + kb + 4);
                bf16x8 av;
                av[0] = (short)f2bf(v0.x); av[1] = (short)f2bf(v0.y);
                av[2] = (short)f2bf(v0.z); av[3] = (short)f2bf(v0.w);
                av[4] = (short)f2bf(v1.x); av[5] = (short)f2bf(v1.y);
                av[6] = (short)f2bf(v1.z); av[7] = (short)f2bf(v1.w);
                a[T][kk] = av;
            }
        }
    } else {
#pragma unroll
        for (int T = 0; T < 2; ++T) {
            const int row = rb + T * 16 + lr;
            const float th = xin[row] * TWO_PI_OVER_L;
            float sv[4], cv[4];
            const float c0 = (float)(hi * 4 + 1);
#pragma unroll
            for (int i = 0; i < 4; ++i)
                sincosf(th * (c0 + (float)i), &sv[i], &cv[i]);
            float s16, c16;
            sincosf(th * 16.0f, &s16, &c16);
#pragma unroll
            for (int kk = 0; kk < 4; ++kk) {
                bf16x8 av;
#pragma unroll
                for (int i = 0; i < 4; ++i) {
                    av[2 * i]     = (short)f2bf(sv[i]);
                    av[2 * i + 1] = (short)f2bf(cv[i]);
                }
                a[T][kk] = av;
                if (kk < 3) {
#pragma unroll
                    for (int i = 0; i < 4; ++i) {
                        const float ns = sv[i] * c16 + cv[i] * s16;
                        cv[i] = cv[i] * c16 - sv[i] * s16;
                        sv[i] = ns;
                    }
                }
            }
        }
    }

    const bf16x8* B1 = (const bf16x8*)w1p;
    const bf16x8* B2 = (const bf16x8*)w2p;

    // ---- GEMM1: H(32x128) = silu(A @ W1 + b1) -> swizzled LDS ----
#pragma unroll
    for (int nt = 0; nt < 8; ++nt) {
        const int n = nt * 16 + lr;
        const float bias = b1[n];
        bf16x8 bfr[4];
#pragma unroll
        for (int kk = 0; kk < 4; ++kk) bfr[kk] = B1[(nt * 4 + kk) * 64 + l];
        f32x4 acc[2];
        acc[0] = f32x4{ bias, bias, bias, bias };
        acc[1] = acc[0];
#pragma unroll
        for (int kk = 0; kk < 4; ++kk) {
            acc[0] = __builtin_amdgcn_mfma_f32_16x16x32_bf16(a[0][kk], bfr[kk], acc[0], 0, 0, 0);
            acc[1] = __builtin_amdgcn_mfma_f32_16x16x32_bf16(a[1][kk], bfr[kk], acc[1], 0, 0, 0);
        }
#pragma unroll
        for (int T = 0; T < 2; ++T)
#pragma unroll
            for (int r = 0; r < 4; ++r) {
                const int row = T * 16 + hi * 4 + r;
                const int byte = (row * 256 + n * 2) ^ ((row & 7) << 4);
                *(unsigned short*)(sh + byte) = f2bf(silu_f(acc[T][r]));
            }
    }

    // ---- A2 fragments from LDS (swizzled ds_read_b128) ----
    bf16x8 a2[2][4];
#pragma unroll
    for (int T = 0; T < 2; ++T)
#pragma unroll
        for (int kk = 0; kk < 4; ++kk) {
            const int row = T * 16 + lr;
            const int byte = (row * 256 + (kk * 32 + kb) * 2) ^ ((row & 7) << 4);
            a2[T][kk] = *(const bf16x8*)(sh + byte);
        }

    // ---- GEMM2: M(32x512) = H @ W2 + b2 ----
#pragma unroll 4
    for (int nt = 0; nt < 32; ++nt) {
        const int n = nt * 16 + lr;
        const float bias = b2[n];
        bf16x8 bfr[4];
#pragma unroll
        for (int kk = 0; kk < 4; ++kk) bfr[kk] = B2[(nt * 4 + kk) * 64 + l];
        f32x4 acc[2];
        acc[0] = f32x4{ bias, bias, bias, bias };
        acc[1] = acc[0];
#pragma unroll
        for (int kk = 0; kk < 4; ++kk) {
            acc[0] = __builtin_amdgcn_mfma_f32_16x16x32_bf16(a2[0][kk], bfr[kk], acc[0], 0, 0, 0);
            acc[1] = __builtin_amdgcn_mfma_f32_16x16x32_bf16(a2[1][kk], bfr[kk], acc[1], 0, 0, 0);
        }
#pragma unroll
        for (int T = 0; T < 2; ++T)
#pragma unroll
            for (int r = 0; r < 4; ++r) {
                const int grow = rb + T * 16 + hi * 4 + r;
                if (MODE == 0 && grow >= nrows) continue;
                out[(size_t)grow * F4 + n] = f2bf(acc[T][r]);
            }
    }
}

// ---------------- per-node gather: 32 threads/node, 4 features/thread ----------------
__global__ __launch_bounds__(256) void gather_kernel(
    const float4* __restrict__ hdr, const int* __restrict__ offsets,
    const unsigned short* __restrict__ m, const unsigned short* __restrict__ phi,
    const float* __restrict__ inv, const float* __restrict__ equiv,
    float* __restrict__ out_v, float* __restrict__ out_s)
{
    const int t = threadIdx.x;
    const int n = blockIdx.x * 8 + (t >> 5);
    const int f0 = (t & 31) * 4;
    const int beg = offsets[n], end = offsets[n + 1];

    float A0[4], A1[4], A2[4], W0[4], W1[4], W2[4], SS[4];
#pragma unroll
    for (int j = 0; j < 4; ++j)
        A0[j] = A1[j] = A2[j] = W0[j] = W1[j] = W2[j] = SS[j] = 0.f;

    for (int si = beg; si < end; ++si) {
        const float4 h = hdr[si];
        const int src = __float_as_int(h.x);
        const float d0 = h.y, d1 = h.z, d2 = h.w;

        const unsigned short* mr = m + (size_t)si * F4 + f0;      // sequential rows
        const unsigned short* pr = phi + (size_t)src * F4 + f0;   // gathered, L2/L3
        float g[4], cg[4], sed[4], sf[4], pg[4], pcg[4], psed[4], psf[4];
        ld4bf(mr, g);  ld4bf(mr + 128, cg);  ld4bf(mr + 256, sed);  ld4bf(mr + 384, sf);
        ld4bf(pr, pg); ld4bf(pr + 128, pcg); ld4bf(pr + 256, psed); ld4bf(pr + 384, psf);

        float ev[12];
        const float* es = equiv + ((size_t)src * F + f0) * 3;
#pragma unroll
        for (int q = 0; q < 3; ++q) *(float4*)&ev[q * 4] = *(const float4*)(es + q * 4);
        float iv[4];
        *(float4*)&iv[0] = *(const float4*)(inv + (size_t)src * F + f0);

#pragma unroll
        for (int j = 0; j < 4; ++j) {
            const float gg   = g[j] * pg[j];
            const float cgg  = cg[j] * pcg[j];
            const float sedv = sed[j] * psed[j];
            const float sfv  = sf[j] * psf[j];
            A0[j] = fmaf(gg, ev[j * 3 + 0], fmaf(sedv, d0, A0[j]));
            A1[j] = fmaf(gg, ev[j * 3 + 1], fmaf(sedv, d1, A1[j]));
            A2[j] = fmaf(gg, ev[j * 3 + 2], fmaf(sedv, d2, A2[j]));
            W0[j] = fmaf(cgg, d0, W0[j]);
            W1[j] = fmaf(cgg, d1, W1[j]);
            W2[j] = fmaf(cgg, d2, W2[j]);
            SS[j] = fmaf(sfv, iv[j], SS[j]);
        }
    }

    // epilogue: residual base + cross(w, equiv[n])
    float bv[12];
    const float* eb = equiv + ((size_t)n * F + f0) * 3;
#pragma unroll
    for (int q = 0; q < 3; ++q) *(float4*)&bv[q * 4] = *(const float4*)(eb + q * 4);
    float ov[12];
#pragma unroll
    for (int j = 0; j < 4; ++j) {
        const float bx = bv[j * 3 + 0], by = bv[j * 3 + 1], bz = bv[j * 3 + 2];
        ov[j * 3 + 0] = bx + A0[j] + (W1[j] * bz - W2[j] * by);
        ov[j * 3 + 1] = by + A1[j] + (W2[j] * bx - W0[j] * bz);
        ov[j * 3 + 2] = bz + A2[j] + (W0[j] * by - W1[j] * bx);
    }
    float* op = out_v + ((size_t)n * F + f0) * 3;
#pragma unroll
    for (int q = 0; q < 3; ++q) *(float4*)(op + q * 4) = *(const float4*)&ov[q * 4];

    float ivb[4];
    *(float4*)&ivb[0] = *(const float4*)(inv + (size_t)n * F + f0);
    float os[4];
#pragma unroll
    for (int j = 0; j < 4; ++j) os[j] = ivb[j] + SS[j];
    *(float4*)(out_s + (size_t)n * F + f0) = *(const float4*)&os[0];
}

extern "C" void kernel_launch(void* const* d_in, const int* in_sizes, int n_in,
                              void* d_out, int out_size, void* d_ws, size_t ws_size,
                              hipStream_t stream)
{
    const int*   ei    = (const int*)d_in[0];
    const float* dist  = (const float*)d_in[1];
    const float* dirv  = (const float*)d_in[2];
    const float* inv   = (const float*)d_in[3];
    const float* equiv = (const float*)d_in[4];
    const float* pw1   = (const float*)d_in[5];
    const float* pb1   = (const float*)d_in[6];
    const float* pw2   = (const float*)d_in[7];
    const float* pb2   = (const float*)d_in[8];
    const float* ww1   = (const float*)d_in[9];
    const float* wb1   = (const float*)d_in[10];
    const float* ww2   = (const float*)d_in[11];
    const float* wb2   = (const float*)d_in[12];

    float* out_v = (float*)d_out;
    float* out_s = out_v + (size_t)N_NODES * F * 3;

    char* base = (char*)d_ws;
    size_t off = 0;
    auto take = [&](size_t bytes) -> void* {
        void* p = base + off;
        off = (off + bytes + 255) & ~(size_t)255;
        return p;
    };
    int* counts  = (int*)take((size_t)N_NODES * 4);
    int* offsets = (int*)take((size_t)(N_NODES + 1) * 4);
    int* cursor  = (int*)take((size_t)N_NODES * 4);
    float* dist_csr = (float*)take((size_t)N_EDGES * 4);
    float4* hdr  = (float4*)take((size_t)N_EDGES * 16);
    unsigned short* phi  = (unsigned short*)take((size_t)N_NODES * F4 * 2);
    unsigned short* ww1p = (unsigned short*)take((size_t)F * F * 2);
    unsigned short* ww2p = (unsigned short*)take((size_t)F * F4 * 2);
    unsigned short* pw1p = (unsigned short*)take((size_t)F * F * 2);
    unsigned short* pw2p = (unsigned short*)take((size_t)F * F4 * 2);
    unsigned short* m    = (unsigned short*)take((size_t)N_EDGES * F4 * 2);
    (void)ws_size;

    hipMemsetAsync(counts, 0, (size_t)N_NODES * 4, stream);
    hist_kernel<<<N_EDGES / 256, 256, 0, stream>>>(ei, counts);
    scan_kernel<<<1, 256, 0, stream>>>(counts, offsets, cursor);
    slot_kernel<<<N_EDGES / 256, 256, 0, stream>>>(ei, dist, dirv, cursor, dist_csr, hdr);

    pack_all_kernel<<<80, 256, 0, stream>>>(ww1, ww1p, ww2, ww2p, pw1, pw1p, pw2, pw2p);

    mlp_gemm_kernel<0><<<(N_NODES + 127) / 128, 256, 0, stream>>>(
        inv, pw1p, pb1, pw2p, pb2, phi, N_NODES);
    mlp_gemm_kernel<1><<<N_EDGES / 128, 256, 0, stream>>>(
        dist_csr, ww1p, wb1, ww2p, wb2, m, N_EDGES);

    gather_kernel<<<N_NODES / 8, 256, 0, stream>>>(
        hdr, offsets, m, phi, inv, equiv, out_v, out_s);
}

// Round 6
// 226.539 us; speedup vs baseline: 1.2441x; 1.1504x over previous
//
#include <hip/hip_runtime.h>
#include <math.h>

#define N_NODES 10000
#define N_EDGES 160000
#define F 128
#define F4 512

static constexpr float TWO_PI_OVER_L = 6.283185307179586f / 10.0f;

typedef __attribute__((ext_vector_type(8))) short bf16x8;
typedef __attribute__((ext_vector_type(4))) float f32x4;

__device__ __forceinline__ float silu_f(float x) { return x / (1.0f + __expf(-x)); }

__device__ __forceinline__ float bf2f(unsigned int u) {
    union { unsigned int i; float f; } x; x.i = u << 16; return x.f;
}
__device__ __forceinline__ unsigned short f2bf(float v) {
    unsigned int u = __float_as_uint(v);
    u += 0x7fff + ((u >> 16) & 1);           // round-to-nearest-even
    return (unsigned short)(u >> 16);
}

__device__ __forceinline__ void ld4bf(const unsigned short* p, float* o) {
    const uint2 u = *(const uint2*)p;
    o[0] = bf2f(u.x & 0xffff); o[1] = bf2f(u.x >> 16);
    o[2] = bf2f(u.y & 0xffff); o[3] = bf2f(u.y >> 16);
}

// ---------------- weight packing: W[K x N] f32 -> fragment-major bf16 ----------------
__device__ __forceinline__ void pack_one(const float* __restrict__ W, int N,
                                         unsigned short* __restrict__ out, int idx)
{
    const int lane = idx & 63;
    const int frag = idx >> 6;
    const int kk = frag & 3, nt = frag >> 2;
    const int k0 = kk * 32 + ((lane >> 4) << 3);
    const int n  = (nt << 4) + (lane & 15);
    unsigned short tmp[8];
#pragma unroll
    for (int j = 0; j < 8; ++j) tmp[j] = f2bf(W[(size_t)(k0 + j) * N + n]);
    uint4* o = (uint4*)(out + (size_t)idx * 8);
    *o = *(const uint4*)tmp;
}

__global__ void pack_all_kernel(
    const float* __restrict__ ww1, unsigned short* __restrict__ ww1p,
    const float* __restrict__ ww2, unsigned short* __restrict__ ww2p,
    const float* __restrict__ pw1, unsigned short* __restrict__ pw1p,
    const float* __restrict__ pw2, unsigned short* __restrict__ pw2p)
{
    const int b = blockIdx.x, t = threadIdx.x;
    if (b < 8)       pack_one(ww1, F,  ww1p, b * 256 + t);
    else if (b < 40) pack_one(ww2, F4, ww2p, (b - 8) * 256 + t);
    else if (b < 48) pack_one(pw1, F,  pw1p, (b - 40) * 256 + t);
    else             pack_one(pw2, F4, pw2p, (b - 48) * 256 + t);
}

// ---------------- CSR build ----------------
__global__ void hist_kernel(const int* __restrict__ ei, int* __restrict__ counts) {
    const int e = blockIdx.x * 256 + threadIdx.x;
    atomicAdd(&counts[ei[N_EDGES + e]], 1);
}

#define SCAN_CHUNK 40
__global__ __launch_bounds__(256) void scan_kernel(const int* __restrict__ counts,
                                                   int* __restrict__ offsets,
                                                   int* __restrict__ cursor)
{
    __shared__ int part[256];
    const int t = threadIdx.x;
    const int base = t * SCAN_CHUNK;
    int s = 0;
    for (int i = 0; i < SCAN_CHUNK; ++i) {
        const int idx = base + i;
        if (idx < N_NODES) s += counts[idx];
    }
    part[t] = s;
    __syncthreads();
    for (int d = 1; d < 256; d <<= 1) {
        int v = 0;
        if (t >= d) v = part[t - d];
        __syncthreads();
        part[t] += v;
        __syncthreads();
    }
    int run = (t == 0) ? 0 : part[t - 1];
    for (int i = 0; i < SCAN_CHUNK; ++i) {
        const int idx = base + i;
        if (idx < N_NODES) {
            offsets[idx] = run;
            cursor[idx] = run;
            run += counts[idx];
        }
    }
    if (t == 255) offsets[N_NODES] = part[255];
}

__global__ void slot_kernel(const int* __restrict__ ei, const float* __restrict__ dist,
                            const float* __restrict__ dirv, int* __restrict__ cursor,
                            float* __restrict__ dist_csr, float4* __restrict__ hdr)
{
    const int e = blockIdx.x * 256 + threadIdx.x;
    const int src = ei[e];
    const int dst = ei[N_EDGES + e];
    const int s = atomicAdd(&cursor[dst], 1);
    dist_csr[s] = dist[e];
    hdr[s] = make_float4(__int_as_float(src),
                         dirv[e * 3 + 0], dirv[e * 3 + 1], dirv[e * 3 + 2]);
}

// ---------------- node-side pre-products: G3 = pg*equiv, q = psf*inv (bf16) --------
__global__ __launch_bounds__(256) void node_prep_kernel(
    const unsigned short* __restrict__ phi,
    const float* __restrict__ equiv, const float* __restrict__ inv,
    unsigned short* __restrict__ G3, unsigned short* __restrict__ q)
{
    const int n = blockIdx.x * 2 + (threadIdx.x >> 7);
    const int f = threadIdx.x & 127;
    const float pg  = bf2f(phi[(size_t)n * F4 + f]);
    const float psf = bf2f(phi[(size_t)n * F4 + 384 + f]);
    const float* e = equiv + ((size_t)n * F + f) * 3;
    G3[(size_t)n * 384 + f]       = f2bf(pg * e[0]);
    G3[(size_t)n * 384 + 128 + f] = f2bf(pg * e[1]);
    G3[(size_t)n * 384 + 256 + f] = f2bf(pg * e[2]);
    q[(size_t)n * F + f] = f2bf(psf * inv[(size_t)n * F + f]);
}

// ---------------- fused 2-layer MLP via MFMA (32 rows/wave) ----------------
template <int MODE>
__global__ __launch_bounds__(256) void mlp_gemm_kernel(
    const float* __restrict__ xin,            // MODE0: inv[N,F]; MODE1: dist_csr[E]
    const unsigned short* __restrict__ w1p, const float* __restrict__ b1,
    const unsigned short* __restrict__ w2p, const float* __restrict__ b2,
    unsigned short* __restrict__ out, const int nrows)
{
    __shared__ char s_h[4][8192];             // per-wave slab: H staging, then C staging
    const int t = threadIdx.x;
    const int w = t >> 6, l = t & 63;
    const int rb = blockIdx.x * 128 + w * 32;
    const int lr = l & 15;
    const int hi = l >> 4;
    const int kb = hi << 3;
    char* sh = s_h[w];

    // ---- A fragments ----
    bf16x8 a[2][4];
    if (MODE == 0) {
#pragma unroll
        for (int T = 0; T < 2; ++T) {
            int row = rb + T * 16 + lr;
            if (row > nrows - 1) row = nrows - 1;
            const float* xr = xin + (size_t)row * F;
#pragma unroll
            for (int kk = 0; kk < 4; ++kk) {
                const float4 v0 = *(const float4*)(xr + kk * 32 + kb);
                const float4 v1 = *(const float4*)(xr + kk * 32 + kb + 4);
                bf16x8 av;
                av[0] = (short)f2bf(v0.x); av[1] = (short)f2bf(v0.y);
                av[2] = (short)f2bf(v0.z); av[3] = (short)f2bf(v0.w);
                av[4] = (short)f2bf(v1.x); av[5] = (short)f2bf(v1.y);
                av[6] = (short)f2bf(v1.z); av[7] = (short)f2bf(v1.w);
                a[T][kk] = av;
            }
        }
    } else {
#pragma unroll
        for (int T = 0; T < 2; ++T) {
            const int row = rb + T * 16 + lr;
            const float th = xin[row] * TWO_PI_OVER_L;
            float sv[4], cv[4];
            const float c0 = (float)(hi * 4 + 1);
#pragma unroll
            for (int i = 0; i < 4; ++i)
                sincosf(th * (c0 + (float)i), &sv[i], &cv[i]);
            float s16, c16;
            sincosf(th * 16.0f, &s16, &c16);
#pragma unroll
            for (int kk = 0; kk < 4; ++kk) {
                bf16x8 av;
#pragma unroll
                for (int i = 0; i < 4; ++i) {
                    av[2 * i]     = (short)f2bf(sv[i]);
                    av[2 * i + 1] = (short)f2bf(cv[i]);
                }
                a[T][kk] = av;
                if (kk < 3) {
#pragma unroll
                    for (int i = 0; i < 4; ++i) {
                        const float ns = sv[i] * c16 + cv[i] * s16;
                        cv[i] = cv[i] * c16 - sv[i] * s16;
                        sv[i] = ns;
                    }
                }
            }
        }
    }

    const bf16x8* B1 = (const bf16x8*)w1p;
    const bf16x8* B2 = (const bf16x8*)w2p;

    // ---- GEMM1: H(32x128) = silu(A @ W1 + b1) -> swizzled LDS ----
#pragma unroll
    for (int nt = 0; nt < 8; ++nt) {
        const int n = nt * 16 + lr;
        const float bias = b1[n];
        bf16x8 bfr[4];
#pragma unroll
        for (int kk = 0; kk < 4; ++kk) bfr[kk] = B1[(nt * 4 + kk) * 64 + l];
        f32x4 acc[2];
        acc[0] = f32x4{ bias, bias, bias, bias };
        acc[1] = acc[0];
#pragma unroll
        for (int kk = 0; kk < 4; ++kk) {
            acc[0] = __builtin_amdgcn_mfma_f32_16x16x32_bf16(a[0][kk], bfr[kk], acc[0], 0, 0, 0);
            acc[1] = __builtin_amdgcn_mfma_f32_16x16x32_bf16(a[1][kk], bfr[kk], acc[1], 0, 0, 0);
        }
#pragma unroll
        for (int T = 0; T < 2; ++T)
#pragma unroll
            for (int r = 0; r < 4; ++r) {
                const int row = T * 16 + hi * 4 + r;
                const int byte = (row * 256 + n * 2) ^ ((row & 7) << 4);
                *(unsigned short*)(sh + byte) = f2bf(silu_f(acc[T][r]));
            }
    }

    // ---- A2 fragments from LDS ----
    bf16x8 a2[2][4];
#pragma unroll
    for (int T = 0; T < 2; ++T)
#pragma unroll
        for (int kk = 0; kk < 4; ++kk) {
            const int row = T * 16 + lr;
            const int byte = (row * 256 + (kk * 32 + kb) * 2) ^ ((row & 7) << 4);
            a2[T][kk] = *(const bf16x8*)(sh + byte);
        }

    // ---- GEMM2: 4 chunks of 128 cols; stage bf16 C in LDS, store uint4 ----
#pragma unroll
    for (int c2 = 0; c2 < 4; ++c2) {
#pragma unroll
        for (int nt8 = 0; nt8 < 8; ++nt8) {
            const int nt = c2 * 8 + nt8;
            const int n = nt * 16 + lr;
            const float bias = b2[n];
            bf16x8 bfr[4];
#pragma unroll
            for (int kk = 0; kk < 4; ++kk) bfr[kk] = B2[(nt * 4 + kk) * 64 + l];
            f32x4 acc[2];
            acc[0] = f32x4{ bias, bias, bias, bias };
            acc[1] = acc[0];
#pragma unroll
            for (int kk = 0; kk < 4; ++kk) {
                acc[0] = __builtin_amdgcn_mfma_f32_16x16x32_bf16(a2[0][kk], bfr[kk], acc[0], 0, 0, 0);
                acc[1] = __builtin_amdgcn_mfma_f32_16x16x32_bf16(a2[1][kk], bfr[kk], acc[1], 0, 0, 0);
            }
            const int coll = nt8 * 16 + lr;
#pragma unroll
            for (int T = 0; T < 2; ++T)
#pragma unroll
                for (int r = 0; r < 4; ++r) {
                    const int rowl = T * 16 + hi * 4 + r;
                    const int byte = (rowl * 256 + coll * 2) ^ ((rowl & 7) << 4);
                    *(unsigned short*)(sh + byte) = f2bf(acc[T][r]);
                }
        }
        // vectorized store of the 32x128 bf16 chunk
#pragma unroll
        for (int i = 0; i < 8; ++i) {
            const int rowl = i * 4 + (l >> 4);
            const int grow = rb + rowl;
            if (MODE == 1 || grow < nrows) {
                const int byte = (rowl * 256 + (l & 15) * 16) ^ ((rowl & 7) << 4);
                const uint4 v = *(const uint4*)(sh + byte);
                *(uint4*)(out + (size_t)grow * F4 + c2 * 128 + (l & 15) * 8) = v;
            }
        }
    }
}

// ---------------- per-node gather: 32 threads/node, 4 features/thread ----------------
__global__ __launch_bounds__(128) void gather_kernel(
    const float4* __restrict__ hdr, const int* __restrict__ offsets,
    const unsigned short* __restrict__ m, const unsigned short* __restrict__ phi,
    const unsigned short* __restrict__ G3, const unsigned short* __restrict__ q,
    const float* __restrict__ inv, const float* __restrict__ equiv,
    float* __restrict__ out_v, float* __restrict__ out_s)
{
    const int t = threadIdx.x;
    const int n = blockIdx.x * 4 + (t >> 5);
    const int f0 = (t & 31) * 4;
    const int beg = offsets[n], end = offsets[n + 1];

    float A0[4], A1[4], A2[4], W0[4], W1[4], W2[4], SS[4];
#pragma unroll
    for (int j = 0; j < 4; ++j)
        A0[j] = A1[j] = A2[j] = W0[j] = W1[j] = W2[j] = SS[j] = 0.f;

    auto process = [&](int si) {
        const float4 h = hdr[si];
        const int src = __float_as_int(h.x);
        const float d0 = h.y, d1 = h.z, d2 = h.w;

        const unsigned short* mr = m + (size_t)si * F4 + f0;          // sequential
        const unsigned short* pr = phi + (size_t)src * F4 + f0;       // gathered
        const unsigned short* gr = G3 + (size_t)src * 384 + f0;
        float g[4], cg[4], sed[4], sf[4], pcg[4], psed[4];
        float g3x[4], g3y[4], g3z[4], qv[4];
        ld4bf(mr, g);        ld4bf(mr + 128, cg);
        ld4bf(mr + 256, sed); ld4bf(mr + 384, sf);
        ld4bf(pr + 128, pcg); ld4bf(pr + 256, psed);
        ld4bf(gr, g3x); ld4bf(gr + 128, g3y); ld4bf(gr + 256, g3z);
        ld4bf(q + (size_t)src * F + f0, qv);

#pragma unroll
        for (int j = 0; j < 4; ++j) {
            const float cgg  = cg[j] * pcg[j];
            const float sedv = sed[j] * psed[j];
            A0[j] = fmaf(g[j], g3x[j], fmaf(sedv, d0, A0[j]));
            A1[j] = fmaf(g[j], g3y[j], fmaf(sedv, d1, A1[j]));
            A2[j] = fmaf(g[j], g3z[j], fmaf(sedv, d2, A2[j]));
            W0[j] = fmaf(cgg, d0, W0[j]);
            W1[j] = fmaf(cgg, d1, W1[j]);
            W2[j] = fmaf(cgg, d2, W2[j]);
            SS[j] = fmaf(sf[j], qv[j], SS[j]);
        }
    };

    int si = beg;
    for (; si + 1 < end; si += 2) { process(si); process(si + 1); }
    if (si < end) process(si);

    // epilogue: residual base + cross(w, equiv[n]) in f32
    float bv[12];
    const float* eb = equiv + ((size_t)n * F + f0) * 3;
#pragma unroll
    for (int qq = 0; qq < 3; ++qq) *(float4*)&bv[qq * 4] = *(const float4*)(eb + qq * 4);
    float ov[12];
#pragma unroll
    for (int j = 0; j < 4; ++j) {
        const float bx = bv[j * 3 + 0], by = bv[j * 3 + 1], bz = bv[j * 3 + 2];
        ov[j * 3 + 0] = bx + A0[j] + (W1[j] * bz - W2[j] * by);
        ov[j * 3 + 1] = by + A1[j] + (W2[j] * bx - W0[j] * bz);
        ov[j * 3 + 2] = bz + A2[j] + (W0[j] * by - W1[j] * bx);
    }
    float* op = out_v + ((size_t)n * F + f0) * 3;
#pragma unroll
    for (int qq = 0; qq < 3; ++qq) *(float4*)(op + qq * 4) = *(const float4*)&ov[qq * 4];

    float ivb[4];
    *(float4*)&ivb[0] = *(const float4*)(inv + (size_t)n * F + f0);
    float os[4];
#pragma unroll
    for (int j = 0; j < 4; ++j) os[j] = ivb[j] + SS[j];
    *(float4*)(out_s + (size_t)n * F + f0) = *(const float4*)&os[0];
}

extern "C" void kernel_launch(void* const* d_in, const int* in_sizes, int n_in,
                              void* d_out, int out_size, void* d_ws, size_t ws_size,
                              hipStream_t stream)
{
    const int*   ei    = (const int*)d_in[0];
    const float* dist  = (const float*)d_in[1];
    const float* dirv  = (const float*)d_in[2];
    const float* inv   = (const float*)d_in[3];
    const float* equiv = (const float*)d_in[4];
    const float* pw1   = (const float*)d_in[5];
    const float* pb1   = (const float*)d_in[6];
    const float* pw2   = (const float*)d_in[7];
    const float* pb2   = (const float*)d_in[8];
    const float* ww1   = (const float*)d_in[9];
    const float* wb1   = (const float*)d_in[10];
    const float* ww2   = (const float*)d_in[11];
    const float* wb2   = (const float*)d_in[12];

    float* out_v = (float*)d_out;
    float* out_s = out_v + (size_t)N_NODES * F * 3;

    char* base = (char*)d_ws;
    size_t off = 0;
    auto take = [&](size_t bytes) -> void* {
        void* p = base + off;
        off = (off + bytes + 255) & ~(size_t)255;
        return p;
    };
    int* counts  = (int*)take((size_t)N_NODES * 4);
    int* offsets = (int*)take((size_t)(N_NODES + 1) * 4);
    int* cursor  = (int*)take((size_t)N_NODES * 4);
    float* dist_csr = (float*)take((size_t)N_EDGES * 4);
    float4* hdr  = (float4*)take((size_t)N_EDGES * 16);
    unsigned short* phi  = (unsigned short*)take((size_t)N_NODES * F4 * 2);
    unsigned short* G3   = (unsigned short*)take((size_t)N_NODES * 384 * 2);
    unsigned short* q    = (unsigned short*)take((size_t)N_NODES * F * 2);
    unsigned short* ww1p = (unsigned short*)take((size_t)F * F * 2);
    unsigned short* ww2p = (unsigned short*)take((size_t)F * F4 * 2);
    unsigned short* pw1p = (unsigned short*)take((size_t)F * F * 2);
    unsigned short* pw2p = (unsigned short*)take((size_t)F * F4 * 2);
    unsigned short* m    = (unsigned short*)take((size_t)N_EDGES * F4 * 2);
    (void)ws_size;

    hipMemsetAsync(counts, 0, (size_t)N_NODES * 4, stream);
    hist_kernel<<<N_EDGES / 256, 256, 0, stream>>>(ei, counts);
    scan_kernel<<<1, 256, 0, stream>>>(counts, offsets, cursor);
    slot_kernel<<<N_EDGES / 256, 256, 0, stream>>>(ei, dist, dirv, cursor, dist_csr, hdr);

    pack_all_kernel<<<80, 256, 0, stream>>>(ww1, ww1p, ww2, ww2p, pw1, pw1p, pw2, pw2p);

    mlp_gemm_kernel<0><<<(N_NODES + 127) / 128, 256, 0, stream>>>(
        inv, pw1p, pb1, pw2p, pb2, phi, N_NODES);
    node_prep_kernel<<<N_NODES / 2, 256, 0, stream>>>(phi, equiv, inv, G3, q);
    mlp_gemm_kernel<1><<<N_EDGES / 128, 256, 0, stream>>>(
        dist_csr, ww1p, wb1, ww2p, wb2, m, N_EDGES);

    gather_kernel<<<N_NODES / 4, 128, 0, stream>>>(
        hdr, offsets, m, phi, G3, q, inv, equiv, out_v, out_s);
}

// Round 7
// 216.471 us; speedup vs baseline: 1.3020x; 1.0465x over previous
//
#include <hip/hip_runtime.h>
#include <math.h>

#define N_NODES 10000
#define N_EDGES 160000
#define F 128
#define F4 512

static constexpr float TWO_PI_OVER_L = 6.283185307179586f / 10.0f;

typedef __attribute__((ext_vector_type(8))) short bf16x8;
typedef __attribute__((ext_vector_type(4))) float f32x4;

__device__ __forceinline__ float silu_f(float x) { return x / (1.0f + __expf(-x)); }

__device__ __forceinline__ float bf2f(unsigned int u) {
    union { unsigned int i; float f; } x; x.i = u << 16; return x.f;
}
__device__ __forceinline__ unsigned short f2bf(float v) {
    unsigned int u = __float_as_uint(v);
    u += 0x7fff + ((u >> 16) & 1);           // round-to-nearest-even
    return (unsigned short)(u >> 16);
}
// packed bf16 pair via HW converter: lo -> bits[15:0], hi -> bits[31:16]
__device__ __forceinline__ unsigned int cvt_pk(float lo, float hi) {
    unsigned int r;
    asm("v_cvt_pk_bf16_f32 %0, %1, %2" : "=v"(r) : "v"(lo), "v"(hi));
    return r;
}

__device__ __forceinline__ void up4(uint2 u, float* o) {
    o[0] = bf2f(u.x & 0xffff); o[1] = bf2f(u.x >> 16);
    o[2] = bf2f(u.y & 0xffff); o[3] = bf2f(u.y >> 16);
}

// ---------------- weight packing (fragment-major bf16) + histogram, fused ---------
__device__ __forceinline__ void pack_one(const float* __restrict__ W, int N,
                                         unsigned short* __restrict__ out, int idx)
{
    const int lane = idx & 63;
    const int frag = idx >> 6;
    const int kk = frag & 3, nt = frag >> 2;
    const int k0 = kk * 32 + ((lane >> 4) << 3);
    const int n  = (nt << 4) + (lane & 15);
    unsigned short tmp[8];
#pragma unroll
    for (int j = 0; j < 8; ++j) tmp[j] = f2bf(W[(size_t)(k0 + j) * N + n]);
    uint4* o = (uint4*)(out + (size_t)idx * 8);
    *o = *(const uint4*)tmp;
}

// blocks [0,8) ww1, [8,40) ww2, [40,48) pw1, [48,80) pw2, [80,705) hist
__global__ void prep_kernel(
    const float* __restrict__ ww1, unsigned short* __restrict__ ww1p,
    const float* __restrict__ ww2, unsigned short* __restrict__ ww2p,
    const float* __restrict__ pw1, unsigned short* __restrict__ pw1p,
    const float* __restrict__ pw2, unsigned short* __restrict__ pw2p,
    const int* __restrict__ ei, int* __restrict__ counts)
{
    const int b = blockIdx.x, t = threadIdx.x;
    if (b < 8)       pack_one(ww1, F,  ww1p, b * 256 + t);
    else if (b < 40) pack_one(ww2, F4, ww2p, (b - 8) * 256 + t);
    else if (b < 48) pack_one(pw1, F,  pw1p, (b - 40) * 256 + t);
    else if (b < 80) pack_one(pw2, F4, pw2p, (b - 48) * 256 + t);
    else {
        const int e = (b - 80) * 256 + t;
        atomicAdd(&counts[ei[N_EDGES + e]], 1);
    }
}

#define SCAN_CHUNK 40
__global__ __launch_bounds__(256) void scan_kernel(const int* __restrict__ counts,
                                                   int* __restrict__ offsets,
                                                   int* __restrict__ cursor)
{
    __shared__ int part[256];
    const int t = threadIdx.x;
    const int base = t * SCAN_CHUNK;
    int s = 0;
    for (int i = 0; i < SCAN_CHUNK; ++i) {
        const int idx = base + i;
        if (idx < N_NODES) s += counts[idx];
    }
    part[t] = s;
    __syncthreads();
    for (int d = 1; d < 256; d <<= 1) {
        int v = 0;
        if (t >= d) v = part[t - d];
        __syncthreads();
        part[t] += v;
        __syncthreads();
    }
    int run = (t == 0) ? 0 : part[t - 1];
    for (int i = 0; i < SCAN_CHUNK; ++i) {
        const int idx = base + i;
        if (idx < N_NODES) {
            offsets[idx] = run;
            cursor[idx] = run;
            run += counts[idx];
        }
    }
    if (t == 255) offsets[N_NODES] = part[255];
}

__global__ void slot_kernel(const int* __restrict__ ei, const float* __restrict__ dist,
                            const float* __restrict__ dirv, int* __restrict__ cursor,
                            float* __restrict__ dist_csr, float4* __restrict__ hdr)
{
    const int e = blockIdx.x * 256 + threadIdx.x;
    const int src = ei[e];
    const int dst = ei[N_EDGES + e];
    const int s = atomicAdd(&cursor[dst], 1);
    dist_csr[s] = dist[e];
    hdr[s] = make_float4(__int_as_float(src),
                         dirv[e * 3 + 0], dirv[e * 3 + 1], dirv[e * 3 + 2]);
}

// ---------------- node-side pre-products: G3 = pg*equiv, q = psf*inv (bf16) --------
__global__ __launch_bounds__(256) void node_prep_kernel(
    const unsigned short* __restrict__ phi,
    const float* __restrict__ equiv, const float* __restrict__ inv,
    unsigned short* __restrict__ G3, unsigned short* __restrict__ q)
{
    const int n = blockIdx.x * 2 + (threadIdx.x >> 7);
    const int f = threadIdx.x & 127;
    const float pg  = bf2f(phi[(size_t)n * F4 + f]);
    const float psf = bf2f(phi[(size_t)n * F4 + 384 + f]);
    const float* e = equiv + ((size_t)n * F + f) * 3;
    G3[(size_t)n * 384 + f]       = f2bf(pg * e[0]);
    G3[(size_t)n * 384 + 128 + f] = f2bf(pg * e[1]);
    G3[(size_t)n * 384 + 256 + f] = f2bf(pg * e[2]);
    q[(size_t)n * F + f] = f2bf(psf * inv[(size_t)n * F + f]);
}

// ---------------- fused 2-layer MLP via MFMA, swapped operands (C^T layout) --------
// lane holds: edge/node = l&15 (+T*16), 4 consecutive out-cols = (l>>4)*4 + r
template <int MODE, int NT>
__global__ __launch_bounds__(256) void mlp_gemm_kernel(
    const float* __restrict__ xin,            // MODE0: inv[N,F]; MODE1: dist_csr[E]
    const unsigned short* __restrict__ w1p, const float* __restrict__ b1,
    const unsigned short* __restrict__ w2p, const float* __restrict__ b2,
    unsigned short* __restrict__ out, const int nrows)
{
    __shared__ char s_h[4][NT * 4096];        // per-wave slab (NT*16 rows x 128 cols bf16)
    const int t = threadIdx.x;
    const int w = t >> 6, l = t & 63;
    const int rb = blockIdx.x * (64 * NT) + w * (16 * NT);
    const int lr = l & 15;
    const int hi = l >> 4;                    // 0..3
    const int kb = hi << 3;                   // 0,8,16,24
    char* sh = s_h[w];

    // ---- A fragments (B-operand role after swap): a[T][kk] ----
    bf16x8 a[NT][4];
    if (MODE == 0) {
#pragma unroll
        for (int T = 0; T < NT; ++T) {
            int row = rb + T * 16 + lr;
            if (row > nrows - 1) row = nrows - 1;
            const float* xr = xin + (size_t)row * F;
#pragma unroll
            for (int kk = 0; kk < 4; ++kk) {
                const float4 v0 = *(const float4*)(xr + kk * 32 + kb);
                const float4 v1 = *(const float4*)(xr + kk * 32 + kb + 4);
                bf16x8 av;
                av[0] = (short)f2bf(v0.x); av[1] = (short)f2bf(v0.y);
                av[2] = (short)f2bf(v0.z); av[3] = (short)f2bf(v0.w);
                av[4] = (short)f2bf(v1.x); av[5] = (short)f2bf(v1.y);
                av[6] = (short)f2bf(v1.z); av[7] = (short)f2bf(v1.w);
                a[T][kk] = av;
            }
        }
    } else {
#pragma unroll
        for (int T = 0; T < NT; ++T) {
            const int row = rb + T * 16 + lr;
            const float th = xin[row] * TWO_PI_OVER_L;
            float sv[4], cv[4];
            const float c0 = (float)(hi * 4 + 1);
#pragma unroll
            for (int i = 0; i < 4; ++i)
                sincosf(th * (c0 + (float)i), &sv[i], &cv[i]);
            float s16, c16;
            sincosf(th * 16.0f, &s16, &c16);
#pragma unroll
            for (int kk = 0; kk < 4; ++kk) {
                bf16x8 av;
#pragma unroll
                for (int i = 0; i < 4; ++i) {
                    av[2 * i]     = (short)f2bf(sv[i]);
                    av[2 * i + 1] = (short)f2bf(cv[i]);
                }
                a[T][kk] = av;
                if (kk < 3) {
#pragma unroll
                    for (int i = 0; i < 4; ++i) {
                        const float ns = sv[i] * c16 + cv[i] * s16;
                        cv[i] = cv[i] * c16 - sv[i] * s16;
                        sv[i] = ns;
                    }
                }
            }
        }
    }

    const bf16x8* B1 = (const bf16x8*)w1p;
    const bf16x8* B2 = (const bf16x8*)w2p;

    // ---- GEMM1: H = silu(A @ W1 + b1) -> swizzled LDS (lane's 4 vals contiguous) ----
#pragma unroll
    for (int nt = 0; nt < 8; ++nt) {
        bf16x8 bfr[4];
#pragma unroll
        for (int kk = 0; kk < 4; ++kk) bfr[kk] = B1[(nt * 4 + kk) * 64 + l];
        const float4 bv = *(const float4*)&b1[nt * 16 + hi * 4];
        f32x4 acc[NT];
#pragma unroll
        for (int T = 0; T < NT; ++T) acc[T] = f32x4{ bv.x, bv.y, bv.z, bv.w };
#pragma unroll
        for (int kk = 0; kk < 4; ++kk)
#pragma unroll
            for (int T = 0; T < NT; ++T)
                acc[T] = __builtin_amdgcn_mfma_f32_16x16x32_bf16(bfr[kk], a[T][kk], acc[T], 0, 0, 0);
#pragma unroll
        for (int T = 0; T < NT; ++T) {
            const int rowl = T * 16 + lr;
            const int byte = (rowl * 256 + nt * 32 + hi * 8) ^ ((rowl & 7) << 4);
            uint2 v;
            v.x = cvt_pk(silu_f(acc[T][0]), silu_f(acc[T][1]));
            v.y = cvt_pk(silu_f(acc[T][2]), silu_f(acc[T][3]));
            *(uint2*)(sh + byte) = v;
        }
    }

    // ---- A2 fragments from LDS (swizzled ds_read_b128) ----
    bf16x8 a2[NT][4];
#pragma unroll
    for (int T = 0; T < NT; ++T)
#pragma unroll
        for (int kk = 0; kk < 4; ++kk) {
            const int rowl = T * 16 + lr;
            const int byte = (rowl * 256 + kk * 64 + hi * 16) ^ ((rowl & 7) << 4);
            a2[T][kk] = *(const bf16x8*)(sh + byte);
        }

    // ---- GEMM2: 4 chunks of 128 cols; stage bf16 C^T in LDS, store uint4 ----
#pragma unroll
    for (int c2 = 0; c2 < 4; ++c2) {
#pragma unroll
        for (int nt8 = 0; nt8 < 8; ++nt8) {
            const int nt = c2 * 8 + nt8;
            bf16x8 bfr[4];
#pragma unroll
            for (int kk = 0; kk < 4; ++kk) bfr[kk] = B2[(nt * 4 + kk) * 64 + l];
            const float4 bv = *(const float4*)&b2[nt * 16 + hi * 4];
            f32x4 acc[NT];
#pragma unroll
            for (int T = 0; T < NT; ++T) acc[T] = f32x4{ bv.x, bv.y, bv.z, bv.w };
#pragma unroll
            for (int kk = 0; kk < 4; ++kk)
#pragma unroll
                for (int T = 0; T < NT; ++T)
                    acc[T] = __builtin_amdgcn_mfma_f32_16x16x32_bf16(bfr[kk], a2[T][kk], acc[T], 0, 0, 0);
#pragma unroll
            for (int T = 0; T < NT; ++T) {
                const int rowl = T * 16 + lr;
                const int byte = (rowl * 256 + nt8 * 32 + hi * 8) ^ ((rowl & 7) << 4);
                uint2 v;
                v.x = cvt_pk(acc[T][0], acc[T][1]);
                v.y = cvt_pk(acc[T][2], acc[T][3]);
                *(uint2*)(sh + byte) = v;
            }
        }
        // vectorized store of the (NT*16) x 128 bf16 chunk
#pragma unroll
        for (int i = 0; i < 4 * NT; ++i) {
            const int rowl = i * 4 + hi;
            const int grow = rb + rowl;
            if (MODE == 1 || grow < nrows) {
                const int byte = (rowl * 256 + lr * 16) ^ ((rowl & 7) << 4);
                const uint4 v = *(const uint4*)(sh + byte);
                *(uint4*)(out + (size_t)grow * F4 + c2 * 128 + lr * 8) = v;
            }
        }
    }
}

// ---------------- per-node gather: 32 threads/node, 4 features/thread, 4-deep ILP ----
__global__ __launch_bounds__(128) void gather_kernel(
    const float4* __restrict__ hdr, const int* __restrict__ offsets,
    const unsigned short* __restrict__ m, const unsigned short* __restrict__ phi,
    const unsigned short* __restrict__ G3, const unsigned short* __restrict__ q,
    const float* __restrict__ inv, const float* __restrict__ equiv,
    float* __restrict__ out_v, float* __restrict__ out_s)
{
    const int t = threadIdx.x;
    const int n = blockIdx.x * 4 + (t >> 5);
    const int f0 = (t & 31) * 4;
    const int beg = offsets[n], end = offsets[n + 1];

    float A0[4], A1[4], A2[4], W0[4], W1[4], W2[4], SS[4];
#pragma unroll
    for (int j = 0; j < 4; ++j)
        A0[j] = A1[j] = A2[j] = W0[j] = W1[j] = W2[j] = SS[j] = 0.f;

    auto fma_edge = [&](const float4& h, const uint2 MG[4], const uint2 PP[2],
                        const uint2 GG[3], const uint2 QQ) {
        const float d0 = h.y, d1 = h.z, d2 = h.w;
        float g[4], cg[4], sed[4], sf[4], pcg[4], psed[4];
        float g3x[4], g3y[4], g3z[4], qv[4];
        up4(MG[0], g);  up4(MG[1], cg); up4(MG[2], sed); up4(MG[3], sf);
        up4(PP[0], pcg); up4(PP[1], psed);
        up4(GG[0], g3x); up4(GG[1], g3y); up4(GG[2], g3z);
        up4(QQ, qv);
#pragma unroll
        for (int j = 0; j < 4; ++j) {
            const float cgg  = cg[j] * pcg[j];
            const float sedv = sed[j] * psed[j];
            A0[j] = fmaf(g[j], g3x[j], fmaf(sedv, d0, A0[j]));
            A1[j] = fmaf(g[j], g3y[j], fmaf(sedv, d1, A1[j]));
            A2[j] = fmaf(g[j], g3z[j], fmaf(sedv, d2, A2[j]));
            W0[j] = fmaf(cgg, d0, W0[j]);
            W1[j] = fmaf(cgg, d1, W1[j]);
            W2[j] = fmaf(cgg, d2, W2[j]);
            SS[j] = fmaf(sf[j], qv[j], SS[j]);
        }
    };

    int si = beg;
    for (; si + 4 <= end; si += 4) {
        float4 H[4];
        uint2 MG[4][4], PP[4][2], GG[4][3], QQ[4];
#pragma unroll
        for (int u = 0; u < 4; ++u) H[u] = hdr[si + u];
#pragma unroll
        for (int u = 0; u < 4; ++u) {
            const int src = __float_as_int(H[u].x);
            const unsigned short* mr = m + (size_t)(si + u) * F4 + f0;
            MG[u][0] = *(const uint2*)mr;
            MG[u][1] = *(const uint2*)(mr + 128);
            MG[u][2] = *(const uint2*)(mr + 256);
            MG[u][3] = *(const uint2*)(mr + 384);
            const unsigned short* pr = phi + (size_t)src * F4 + f0;
            PP[u][0] = *(const uint2*)(pr + 128);
            PP[u][1] = *(const uint2*)(pr + 256);
            const unsigned short* gr = G3 + (size_t)src * 384 + f0;
            GG[u][0] = *(const uint2*)gr;
            GG[u][1] = *(const uint2*)(gr + 128);
            GG[u][2] = *(const uint2*)(gr + 256);
            QQ[u] = *(const uint2*)(q + (size_t)src * F + f0);
        }
#pragma unroll
        for (int u = 0; u < 4; ++u) fma_edge(H[u], MG[u], PP[u], GG[u], QQ[u]);
    }
    for (; si < end; ++si) {
        const float4 h = hdr[si];
        const int src = __float_as_int(h.x);
        uint2 MG[4], PP[2], GG[3], QQ;
        const unsigned short* mr = m + (size_t)si * F4 + f0;
        MG[0] = *(const uint2*)mr;
        MG[1] = *(const uint2*)(mr + 128);
        MG[2] = *(const uint2*)(mr + 256);
        MG[3] = *(const uint2*)(mr + 384);
        const unsigned short* pr = phi + (size_t)src * F4 + f0;
        PP[0] = *(const uint2*)(pr + 128);
        PP[1] = *(const uint2*)(pr + 256);
        const unsigned short* gr = G3 + (size_t)src * 384 + f0;
        GG[0] = *(const uint2*)gr;
        GG[1] = *(const uint2*)(gr + 128);
        GG[2] = *(const uint2*)(gr + 256);
        QQ = *(const uint2*)(q + (size_t)src * F + f0);
        fma_edge(h, MG, PP, GG, QQ);
    }

    // epilogue: residual base + cross(w, equiv[n]) in f32
    float bv[12];
    const float* eb = equiv + ((size_t)n * F + f0) * 3;
#pragma unroll
    for (int qq = 0; qq < 3; ++qq) *(float4*)&bv[qq * 4] = *(const float4*)(eb + qq * 4);
    float ov[12];
#pragma unroll
    for (int j = 0; j < 4; ++j) {
        const float bx = bv[j * 3 + 0], by = bv[j * 3 + 1], bz = bv[j * 3 + 2];
        ov[j * 3 + 0] = bx + A0[j] + (W1[j] * bz - W2[j] * by);
        ov[j * 3 + 1] = by + A1[j] + (W2[j] * bx - W0[j] * bz);
        ov[j * 3 + 2] = bz + A2[j] + (W0[j] * by - W1[j] * bx);
    }
    float* op = out_v + ((size_t)n * F + f0) * 3;
#pragma unroll
    for (int qq = 0; qq < 3; ++qq) *(float4*)(op + qq * 4) = *(const float4*)&ov[qq * 4];

    float ivb[4];
    *(float4*)&ivb[0] = *(const float4*)(inv + (size_t)n * F + f0);
    float os[4];
#pragma unroll
    for (int j = 0; j < 4; ++j) os[j] = ivb[j] + SS[j];
    *(float4*)(out_s + (size_t)n * F + f0) = *(const float4*)&os[0];
}

extern "C" void kernel_launch(void* const* d_in, const int* in_sizes, int n_in,
                              void* d_out, int out_size, void* d_ws, size_t ws_size,
                              hipStream_t stream)
{
    const int*   ei    = (const int*)d_in[0];
    const float* dist  = (const float*)d_in[1];
    const float* dirv  = (const float*)d_in[2];
    const float* inv   = (const float*)d_in[3];
    const float* equiv = (const float*)d_in[4];
    const float* pw1   = (const float*)d_in[5];
    const float* pb1   = (const float*)d_in[6];
    const float* pw2   = (const float*)d_in[7];
    const float* pb2   = (const float*)d_in[8];
    const float* ww1   = (const float*)d_in[9];
    const float* wb1   = (const float*)d_in[10];
    const float* ww2   = (const float*)d_in[11];
    const float* wb2   = (const float*)d_in[12];

    float* out_v = (float*)d_out;
    float* out_s = out_v + (size_t)N_NODES * F * 3;

    char* base = (char*)d_ws;
    size_t off = 0;
    auto take = [&](size_t bytes) -> void* {
        void* p = base + off;
        off = (off + bytes + 255) & ~(size_t)255;
        return p;
    };
    int* counts  = (int*)take((size_t)N_NODES * 4);
    int* offsets = (int*)take((size_t)(N_NODES + 1) * 4);
    int* cursor  = (int*)take((size_t)N_NODES * 4);
    float* dist_csr = (float*)take((size_t)N_EDGES * 4);
    float4* hdr  = (float4*)take((size_t)N_EDGES * 16);
    unsigned short* phi  = (unsigned short*)take((size_t)N_NODES * F4 * 2);
    unsigned short* G3   = (unsigned short*)take((size_t)N_NODES * 384 * 2);
    unsigned short* q    = (unsigned short*)take((size_t)N_NODES * F * 2);
    unsigned short* ww1p = (unsigned short*)take((size_t)F * F * 2);
    unsigned short* ww2p = (unsigned short*)take((size_t)F * F4 * 2);
    unsigned short* pw1p = (unsigned short*)take((size_t)F * F * 2);
    unsigned short* pw2p = (unsigned short*)take((size_t)F * F4 * 2);
    unsigned short* m    = (unsigned short*)take((size_t)N_EDGES * F4 * 2);
    (void)ws_size;

    hipMemsetAsync(counts, 0, (size_t)N_NODES * 4, stream);
    prep_kernel<<<80 + N_EDGES / 256, 256, 0, stream>>>(
        ww1, ww1p, ww2, ww2p, pw1, pw1p, pw2, pw2p, ei, counts);
    scan_kernel<<<1, 256, 0, stream>>>(counts, offsets, cursor);
    slot_kernel<<<N_EDGES / 256, 256, 0, stream>>>(ei, dist, dirv, cursor, dist_csr, hdr);

    mlp_gemm_kernel<0, 1><<<(N_NODES + 63) / 64, 256, 0, stream>>>(
        inv, pw1p, pb1, pw2p, pb2, phi, N_NODES);
    node_prep_kernel<<<N_NODES / 2, 256, 0, stream>>>(phi, equiv, inv, G3, q);
    mlp_gemm_kernel<1, 2><<<N_EDGES / 128, 256, 0, stream>>>(
        dist_csr, ww1p, wb1, ww2p, wb2, m, N_EDGES);

    gather_kernel<<<N_NODES / 4, 128, 0, stream>>>(
        hdr, offsets, m, phi, G3, q, inv, equiv, out_v, out_s);
}